// Round 1
// baseline (2517.213 us; speedup 1.0000x reference)
//
#include <hip/hip_runtime.h>
#include <hip/hip_bf16.h>
#include <stdint.h>

// Problem shape (fixed by reference)
#define B_DIM 2
#define S_DIM 2048
#define D_DIM 4096
#define V_DIM 32000
#define M_DIM (B_DIM * S_DIM)        // 4096 rows into the GEMM
#define OUT_ROWS (B_DIM * (S_DIM-1)) // 4094 output rows after shift

typedef __hip_bfloat16 bf16;
typedef __bf16 bf16x8 __attribute__((ext_vector_type(8)));
typedef float floatx4 __attribute__((ext_vector_type(4)));

// ---- async global->LDS (16B granules); LDS dst must be wave-uniform base + lane*16
__device__ __forceinline__ void async16(const bf16* g, bf16* l) {
    __builtin_amdgcn_global_load_lds(
        (const __attribute__((address_space(1))) void*)g,
        (__attribute__((address_space(3))) void*)l,
        16, 0, 0);
}

// ---------------- RMSNorm + cast to bf16 ----------------
// one block (256 threads) per row of 4096 floats
__global__ void rmsnorm_cast_kernel(const float* __restrict__ x,
                                    const float* __restrict__ w,
                                    bf16* __restrict__ h) {
    const int row = blockIdx.x;
    const int t = threadIdx.x;
    const float* xr = x + (size_t)row * D_DIM;

    float4 vals[4];
    float ss = 0.f;
#pragma unroll
    for (int i = 0; i < 4; ++i) {
        float4 v = ((const float4*)xr)[t + i * 256];
        vals[i] = v;
        ss += v.x * v.x + v.y * v.y + v.z * v.z + v.w * v.w;
    }
    // wave-64 reduction
#pragma unroll
    for (int off = 32; off; off >>= 1) ss += __shfl_down(ss, off, 64);
    __shared__ float wsum[4];
    const int lane = t & 63, wv = t >> 6;
    if (lane == 0) wsum[wv] = ss;
    __syncthreads();
    const float var = (wsum[0] + wsum[1] + wsum[2] + wsum[3]) * (1.0f / D_DIM);
    const float scale = rsqrtf(var + 1e-6f);

    bf16* hr = h + (size_t)row * D_DIM;
#pragma unroll
    for (int i = 0; i < 4; ++i) {
        const int f4 = t + i * 256;
        float4 v = vals[i];
        float4 wv4 = ((const float4*)w)[f4];
        ushort4 pk;
        bf16 b0 = __float2bfloat16(v.x * scale * wv4.x);
        bf16 b1 = __float2bfloat16(v.y * scale * wv4.y);
        bf16 b2 = __float2bfloat16(v.z * scale * wv4.z);
        bf16 b3 = __float2bfloat16(v.w * scale * wv4.w);
        pk.x = *(unsigned short*)&b0;
        pk.y = *(unsigned short*)&b1;
        pk.z = *(unsigned short*)&b2;
        pk.w = *(unsigned short*)&b3;
        ((ushort4*)hr)[f4] = pk;
    }
}

// ---------------- W fp32 -> bf16 cast ----------------
__global__ void wcast_kernel(const float* __restrict__ W, bf16* __restrict__ Wb) {
    const size_t i = (size_t)blockIdx.x * 256 + threadIdx.x; // float4 index
    float4 v = ((const float4*)W)[i];
    ushort4 pk;
    bf16 b0 = __float2bfloat16(v.x);
    bf16 b1 = __float2bfloat16(v.y);
    bf16 b2 = __float2bfloat16(v.z);
    bf16 b3 = __float2bfloat16(v.w);
    pk.x = *(unsigned short*)&b0;
    pk.y = *(unsigned short*)&b1;
    pk.z = *(unsigned short*)&b2;
    pk.w = *(unsigned short*)&b3;
    ((ushort4*)Wb)[i] = pk;
}

// ---------------- bf16 MFMA GEMM (C = A * B^T), shifted store ----------------
// A: h_bf16 [4096][4096] row-major (K-contiguous)
// B: W_bf16 [32000][4096] row-major (K-contiguous == B^T layout)
// C: shift_logits [4094][32000]; GEMM row m -> out row (m>>11)*2047 + (m&2047), skip s==2047
#define BM 128
#define BN 128
#define BK 32

__global__ __launch_bounds__(256) void gemm_kernel(const bf16* __restrict__ A,
                                                   const bf16* __restrict__ Bw,
                                                   float* __restrict__ Cout) {
    __shared__ __align__(16) bf16 As[BM * BK]; // 8 KB
    __shared__ __align__(16) bf16 Bs[BN * BK]; // 8 KB

    // N-panel-major: 32 consecutive blocks share one W panel (L2/LLC reuse)
    const int bid = blockIdx.x;
    const int bm = bid & 31;   // 32 M tiles
    const int bn = bid >> 5;   // 250 N tiles
    const int m0 = bm * BM;
    const int n0 = bn * BN;

    const int t = threadIdx.x;
    const int lane = t & 63;
    const int wv = t >> 6;          // 4 waves
    const int wm = (wv & 1) * 64;   // wave tile: 64x64
    const int wn = (wv >> 1) * 64;
    const int quad = lane >> 4;
    const int l15 = lane & 15;

    floatx4 acc[4][4] = {};

    // staging granule: gi in [0,512), row = gi>>2 (64B rows = 4x16B), kc = (gi&3)*8
    const int gi0 = t;
    const int gi1 = t + 256;

    for (int kt = 0; kt < D_DIM / BK; ++kt) {
        const int k0 = kt * BK;
        {
            const int row0 = gi0 >> 2, kc0 = (gi0 & 3) * 8;
            const int row1 = gi1 >> 2, kc1 = (gi1 & 3) * 8;
            async16(&A[(size_t)(m0 + row0) * D_DIM + k0 + kc0], &As[gi0 * 8]);
            async16(&A[(size_t)(m0 + row1) * D_DIM + k0 + kc1], &As[gi1 * 8]);
            async16(&Bw[(size_t)(n0 + row0) * D_DIM + k0 + kc0], &Bs[gi0 * 8]);
            async16(&Bw[(size_t)(n0 + row1) * D_DIM + k0 + kc1], &Bs[gi1 * 8]);
        }
        __syncthreads(); // drains vmcnt(0): LDS tiles ready

        bf16x8 af[4], bfr[4];
#pragma unroll
        for (int i = 0; i < 4; ++i) {
            af[i]  = *(const bf16x8*)&As[(wm + i * 16 + l15) * BK + quad * 8];
            bfr[i] = *(const bf16x8*)&Bs[(wn + i * 16 + l15) * BK + quad * 8];
        }
#pragma unroll
        for (int mi = 0; mi < 4; ++mi)
#pragma unroll
            for (int ni = 0; ni < 4; ++ni)
                acc[mi][ni] = __builtin_amdgcn_mfma_f32_16x16x32_bf16(
                    af[mi], bfr[ni], acc[mi][ni], 0, 0, 0);
        __syncthreads(); // protect LDS before next stage
    }

    // epilogue: C/D layout col = lane&15 (n), row = quad*4 + reg (m)
#pragma unroll
    for (int mi = 0; mi < 4; ++mi) {
#pragma unroll
        for (int r = 0; r < 4; ++r) {
            const int m = m0 + wm + mi * 16 + quad * 4 + r;
            const int s = m & (S_DIM - 1);
            if (s == S_DIM - 1) continue; // shifted out
            const int orow = (m >> 11) * (S_DIM - 1) + s;
            float* cp = Cout + (size_t)orow * V_DIM + n0 + wn;
#pragma unroll
            for (int ni = 0; ni < 4; ++ni)
                cp[ni * 16 + l15] = acc[mi][ni][r];
        }
    }
}

// ---------------- shifted labels (as float, per harness output convention) ----------------
__global__ void labels_kernel(const int* __restrict__ labels, float* __restrict__ out) {
    const int r = blockIdx.x * 256 + threadIdx.x;
    if (r >= OUT_ROWS) return;
    const int b = r / (S_DIM - 1);
    const int s = r % (S_DIM - 1);
    out[r] = (float)labels[b * S_DIM + s + 1];
}

extern "C" void kernel_launch(void* const* d_in, const int* in_sizes, int n_in,
                              void* d_out, int out_size, void* d_ws, size_t ws_size,
                              hipStream_t stream) {
    const float* x      = (const float*)d_in[0]; // hidden_states [2,2048,4096] fp32
    const float* nw     = (const float*)d_in[1]; // norm_weight [4096] fp32
    const float* W      = (const float*)d_in[2]; // lm_head_weight [32000,4096] fp32
    // d_in[3] attention_mask: all-ones, unused by reference math
    const int*   labels = (const int*)d_in[4];   // labels [2,2048]

    float* logits_out = (float*)d_out;                              // [4094][32000]
    float* labels_out = logits_out + (size_t)OUT_ROWS * V_DIM;      // [4094]

    bf16* h  = (bf16*)d_ws;                         // 4096*4096*2  = 33.5 MB
    bf16* Wb = h + (size_t)M_DIM * D_DIM;           // 32000*4096*2 = 262 MB

    rmsnorm_cast_kernel<<<M_DIM, 256, 0, stream>>>(x, nw, h);
    wcast_kernel<<<(int)((size_t)V_DIM * D_DIM / 4 / 256), 256, 0, stream>>>(W, Wb);
    gemm_kernel<<<32 * (V_DIM / BN), 256, 0, stream>>>(h, Wb, logits_out);
    labels_kernel<<<(OUT_ROWS + 255) / 256, 256, 0, stream>>>(labels, labels_out);
}